// Round 5
// baseline (301.543 us; speedup 1.0000x reference)
//
#include <hip/hip_runtime.h>

// Problem constants (match reference)
#define BATCH 32
#define T_IN 1024
#define TP 1025      // T+1 (phoneme + silence token)
#define EMB 384
#define GROUPS 4
#define GC 96        // channels per group

typedef __attribute__((ext_vector_type(8))) short short8;   // 8 bf16 (4 VGPRs)
typedef __attribute__((ext_vector_type(4))) float f32x4;    // 4 fp32 acc / 16B vec

#define N_WPACK (GROUPS * 9 * 6 * 64 * 8)   // 110592 bf16 elements
#define PREP_BLOCKS ((N_WPACK + 255) / 256) // 432
#define CONV_TILES 17                       // t-tiles of 64 covering TP=1025

__device__ __forceinline__ unsigned short f2bf(float f) {
    union { float f; unsigned u; } v; v.f = f;
    unsigned u = v.u + 0x7fffu + ((v.u >> 16) & 1u);  // RNE
    return (unsigned short)(u >> 16);
}

// ---------------------------------------------------------------------------
// Kernel 0 (fused): blocks [0,432) pack w1 -> bf16 MFMA B-frag layout;
// blocks [432,464) do per-batch cumsum + scatter frame->token idx.
// idx[b][t] = token j for cum[j-1] <= t < cum[j]; 0xFFFF past total.
// ---------------------------------------------------------------------------
__global__ __launch_bounds__(256) void prep_scan_kernel(const float* __restrict__ w1,
                                                        const int* __restrict__ dur,
                                                        unsigned short* __restrict__ wpack,
                                                        unsigned short* __restrict__ idx,
                                                        int t_out) {
    __shared__ int scum[TP];
    const int tid = threadIdx.x;

    if (blockIdx.x < PREP_BLOCKS) {
        int i = blockIdx.x * 256 + tid;
        if (i >= N_WPACK) return;
        int j = i & 7;
        int lane = (i >> 3) & 63;
        int rest = i >> 9;
        int nt = rest % 6; rest /= 6;
        int ks = rest % 9;
        int g = rest / 9;
        int oc = nt * 16 + (lane & 15);
        int kk = ks * 32 + (lane >> 4) * 8 + j;
        int k = kk / 96, ic = kk % 96;
        wpack[i] = f2bf(w1[((size_t)(g * GC + oc) * GC + ic) * 3 + k]);
        return;
    }

    const int b = blockIdx.x - PREP_BLOCKS;
    if (tid < 64) {
        const int* d = dur + b * TP;
        int offset = 0;
        for (int r = 0; r < 17; ++r) {
            int i2 = r * 64 + tid;
            int v = (i2 < TP) ? d[i2] : 0;
            int s = v;
#pragma unroll
            for (int off = 1; off < 64; off <<= 1) {
                int n = __shfl_up(s, off, 64);
                if (tid >= off) s += n;
            }
            if (i2 < TP) scum[i2] = s + offset;
            offset += __shfl(s, 63, 64);
        }
    }
    __syncthreads();

    unsigned short* ib = idx + (size_t)b * t_out;
    for (int j = tid; j < TP; j += 256) {
        int c = scum[j];
        int lo = j ? scum[j - 1] : 0;
        for (int f = lo; f < c; ++f) ib[f] = (unsigned short)j;
    }
    const int total = scum[TP - 1];
    for (int t = total + tid; t < t_out; t += 256) ib[t] = 0xFFFFu;
}

// ---------------------------------------------------------------------------
// Kernel 1 (fused conv + gather): one dispatch, partitioned by blockIdx.x.
//   blockIdx.x < 17  : grouped conv (k=3,pad 1) + ReLU + 1x1 conv via bf16
//                      MFMA (4 waves = 4 groups, 4x6 MFMA reg tile each),
//                      writing pred[b][t0..t0+63] directly.
//   blockIdx.x >= 17 : streaming length-regulate gather, grid-stride over
//                      float4-PAIRS (32 B/thread/iter, ~4 iters).
// Both branches depend only on prep_scan outputs, so their blocks co-schedule:
// the conv's ~20 us hides inside the gather's HBM-bound window (m114 overlap).
// Static LDS 52 KB caps residency at 3 blocks/CU = 12 waves/CU -> ~25 MB of
// in-flight traffic device-wide, ample for ~6.5 TB/s.
// ---------------------------------------------------------------------------
__global__ __launch_bounds__(256) void conv_gather_kernel(const float* __restrict__ phoneme,
                                                          const float* __restrict__ silence,
                                                          const float* __restrict__ b1,
                                                          const float* __restrict__ w2,
                                                          const float* __restrict__ b2,
                                                          const unsigned short* __restrict__ wpack,
                                                          const unsigned short* __restrict__ idx,
                                                          float* __restrict__ pred,
                                                          float* __restrict__ out,
                                                          int t_out, int gx) {
    __shared__ __align__(16) unsigned short xs[66][392];  // conv: rows t0-1..t0+64
    __shared__ float red[4][64];

    const int b = blockIdx.y;
    const int tid = threadIdx.x;

    if (blockIdx.x >= CONV_TILES) {
        // ---------------- gather branch ----------------
        const int bx = blockIdx.x - CONV_TILES;
        const int P = t_out * 48;  // float4-pairs per batch
        const unsigned short* ib = idx + (size_t)b * t_out;
        const f32x4* ph = (const f32x4*)phoneme + (size_t)b * T_IN * 96;
        const f32x4* s4 = (const f32x4*)silence;
        f32x4* ob = (f32x4*)out + (size_t)b * t_out * 96;
        for (int p = bx * 256 + tid; p < P; p += gx * 256) {
            int fl = p / 48;
            int v = (p - fl * 48) * 2;
            unsigned short id = ib[fl];
            f32x4 v0, v1;
            if (id == 0xFFFFu) {
                v0 = (f32x4){0.f, 0.f, 0.f, 0.f};
                v1 = v0;
            } else if (id == T_IN) {
                v0 = s4[v]; v1 = s4[v + 1];
            } else {
                const f32x4* pp = ph + (size_t)id * 96 + v;
                v0 = pp[0]; v1 = pp[1];
            }
            f32x4* o = ob + (size_t)fl * 96 + v;
            o[0] = v0; o[1] = v1;
        }
        return;
    }

    // ---------------- conv branch ----------------
    const int t0 = blockIdx.x * 64;

    // Stage 66 full rows (fp32 -> bf16), coalesced full-row float4 reads
    for (int e = tid; e < 66 * 96; e += 256) {
        int row = e / 96;
        int v = e - row * 96;
        int r = t0 - 1 + row;
        float4 val;
        if (r < 0 || r > T_IN) {
            val = make_float4(0.f, 0.f, 0.f, 0.f);
        } else if (r == T_IN) {
            val = *(const float4*)(silence + v * 4);
        } else {
            val = *(const float4*)(phoneme + ((size_t)(b * T_IN + r)) * EMB + v * 4);
        }
        ushort4 pk;
        pk.x = f2bf(val.x); pk.y = f2bf(val.y); pk.z = f2bf(val.z); pk.w = f2bf(val.w);
        *(ushort4*)&xs[row][v * 4] = pk;
    }
    __syncthreads();

    const int g = tid >> 6;     // wave = group
    const int lane = tid & 63;
    const int quad = lane >> 4;
    const int lr = lane & 15;

    f32x4 acc[4][6];
#pragma unroll
    for (int mt = 0; mt < 4; ++mt)
#pragma unroll
        for (int nt = 0; nt < 6; ++nt) acc[mt][nt] = (f32x4){0.f, 0.f, 0.f, 0.f};

    const unsigned short* wg = wpack + (size_t)g * 9 * 6 * 512;

#pragma unroll
    for (int ks = 0; ks < 9; ++ks) {
        const int tap = ks / 3;                               // kstep-uniform
        const int col = g * GC + 32 * (ks % 3) + quad * 8;    // channel offset
        short8 a[4];
#pragma unroll
        for (int mt = 0; mt < 4; ++mt)
            a[mt] = *(const short8*)&xs[mt * 16 + lr + tap][col];
#pragma unroll
        for (int nt = 0; nt < 6; ++nt) {
            short8 bf = *(const short8*)(wg + ((size_t)(ks * 6 + nt) * 64 + lane) * 8);
#pragma unroll
            for (int mt = 0; mt < 4; ++mt)
                acc[mt][nt] = __builtin_amdgcn_mfma_f32_16x16x32_bf16(a[mt], bf, acc[mt][nt], 0, 0, 0);
        }
    }

    // Epilogue: bias + ReLU + w2-dot partials; m = mt*16 + quad*4 + reg, oc col = lr
    float s[4][4];
#pragma unroll
    for (int mt = 0; mt < 4; ++mt)
#pragma unroll
        for (int reg = 0; reg < 4; ++reg) s[mt][reg] = 0.f;
#pragma unroll
    for (int nt = 0; nt < 6; ++nt) {
        int oc = g * GC + nt * 16 + lr;
        float bias = b1[oc];
        float wc = w2[oc];
#pragma unroll
        for (int mt = 0; mt < 4; ++mt)
#pragma unroll
            for (int reg = 0; reg < 4; ++reg) {
                float h = acc[mt][nt][reg] + bias;
                h = h > 0.f ? h : 0.f;
                s[mt][reg] += wc * h;
            }
    }
    // butterfly-sum across the 16 lr lanes (stays within each 16-lane group)
#pragma unroll
    for (int off = 1; off < 16; off <<= 1)
#pragma unroll
        for (int mt = 0; mt < 4; ++mt)
#pragma unroll
            for (int reg = 0; reg < 4; ++reg)
                s[mt][reg] += __shfl_xor(s[mt][reg], off, 64);
#pragma unroll
    for (int mt = 0; mt < 4; ++mt)
#pragma unroll
        for (int reg = 0; reg < 4; ++reg)
            if (lr == mt * 4 + reg) red[g][mt * 16 + quad * 4 + reg] = s[mt][reg];
    __syncthreads();

    if (tid < 64) {
        int t = t0 + tid;
        if (t < TP)
            pred[b * TP + t] = red[0][tid] + red[1][tid] + red[2][tid] + red[3][tid] + b2[0];
    }
}

// ---------------------------------------------------------------------------
extern "C" void kernel_launch(void* const* d_in, const int* in_sizes, int n_in,
                              void* d_out, int out_size, void* d_ws, size_t ws_size,
                              hipStream_t stream) {
    const float* phoneme = (const float*)d_in[0];
    const float* silence = (const float*)d_in[1];
    const float* conv1_w = (const float*)d_in[2];
    const float* conv1_b = (const float*)d_in[3];
    const float* conv2_w = (const float*)d_in[4];
    const float* conv2_b = (const float*)d_in[5];
    const int* durations = (const int*)d_in[6];
    // d_in[7] = t_out on device; derive from out_size host-side instead.
    const int t_out = (out_size - BATCH * TP) / (BATCH * EMB);

    float* out_expanded = (float*)d_out;                            // [B, t_out, EMB]
    float* out_pred = (float*)d_out + (size_t)BATCH * t_out * EMB;  // [B, TP]

    // Workspace: idx [B][t_out] ushort, then wpack (16B-aligned)
    unsigned short* idx = (unsigned short*)d_ws;
    size_t idx_bytes = ((size_t)BATCH * t_out * sizeof(unsigned short) + 255) & ~(size_t)255;
    unsigned short* wpack = (unsigned short*)((char*)d_ws + idx_bytes);

    // gather x-extent: ~4 float4-pairs (128 B) per thread
    const int P = t_out * 48;
    const int gx = (P + 1023) / 1024;

    prep_scan_kernel<<<PREP_BLOCKS + BATCH, 256, 0, stream>>>(
        conv1_w, durations, wpack, idx, t_out);
    conv_gather_kernel<<<dim3(CONV_TILES + gx, BATCH), 256, 0, stream>>>(
        phoneme, silence, conv1_b, conv2_w, conv2_b, wpack, idx,
        out_pred, out_expanded, t_out, gx);
}

// Round 6
// 272.533 us; speedup vs baseline: 1.1064x; 1.1064x over previous
//
#include <hip/hip_runtime.h>

// Problem constants (match reference)
#define BATCH 32
#define T_IN 1024
#define TP 1025      // T+1 (phoneme + silence token)
#define EMB 384
#define GROUPS 4
#define GC 96        // channels per group

typedef __attribute__((ext_vector_type(8))) short short8;   // 8 bf16 (4 VGPRs)
typedef __attribute__((ext_vector_type(4))) float f32x4;    // 4 fp32 acc / 16B vec

#define N_WPACK (GROUPS * 9 * 6 * 64 * 8)   // 110592 bf16 elements
#define PREP_BLOCKS ((N_WPACK + 255) / 256) // 432
#define SCAT_SLICES 8                        // scatter blocks per batch
#define TOK_PER_SLICE 129                    // 8*129 = 1032 >= 1025

__device__ __forceinline__ unsigned short f2bf(float f) {
    union { float f; unsigned u; } v; v.f = f;
    unsigned u = v.u + 0x7fffu + ((v.u >> 16) & 1u);  // RNE
    return (unsigned short)(u >> 16);
}

// ---------------------------------------------------------------------------
// Kernel 0 (fused): blocks [0,432) pack w1 -> bf16 MFMA B-frag layout;
// blocks [432, 432+256) : per-batch cumsum + scatter frame->token idx,
// 8 slice-blocks per batch (each redoes the cheap wave-scan, scatters its
// 129-token slice, and fills its share of the 0xFFFF tail).
// ---------------------------------------------------------------------------
__global__ __launch_bounds__(256) void prep_scan_kernel(const float* __restrict__ w1,
                                                        const int* __restrict__ dur,
                                                        unsigned short* __restrict__ wpack,
                                                        unsigned short* __restrict__ idx,
                                                        int t_out) {
    __shared__ int scum[TP];
    const int tid = threadIdx.x;

    if (blockIdx.x < PREP_BLOCKS) {
        int i = blockIdx.x * 256 + tid;
        if (i >= N_WPACK) return;
        int j = i & 7;
        int lane = (i >> 3) & 63;
        int rest = i >> 9;
        int nt = rest % 6; rest /= 6;
        int ks = rest % 9;
        int g = rest / 9;
        int oc = nt * 16 + (lane & 15);
        int kk = ks * 32 + (lane >> 4) * 8 + j;
        int k = kk / 96, ic = kk % 96;
        wpack[i] = f2bf(w1[((size_t)(g * GC + oc) * GC + ic) * 3 + k]);
        return;
    }

    const int sb = blockIdx.x - PREP_BLOCKS;     // 0..255
    const int b = sb >> 3;                       // batch
    const int slice = sb & 7;                    // slice within batch

    if (tid < 64) {
        const int* d = dur + b * TP;
        int offset = 0;
        for (int r = 0; r < 17; ++r) {
            int i2 = r * 64 + tid;
            int v = (i2 < TP) ? d[i2] : 0;
            int s = v;
#pragma unroll
            for (int off = 1; off < 64; off <<= 1) {
                int n = __shfl_up(s, off, 64);
                if (tid >= off) s += n;
            }
            if (i2 < TP) scum[i2] = s + offset;
            offset += __shfl(s, 63, 64);
        }
    }
    __syncthreads();

    unsigned short* ib = idx + (size_t)b * t_out;
    const int j0 = slice * TOK_PER_SLICE;
    const int j1 = min(TP, j0 + TOK_PER_SLICE);
    for (int j = j0 + tid; j < j1; j += 256) {
        int c = scum[j];
        int lo = j ? scum[j - 1] : 0;
        for (int f = lo; f < c; ++f) ib[f] = (unsigned short)j;
    }
    const int total = scum[TP - 1];
    for (int t = total + slice * 256 + tid; t < t_out; t += SCAT_SLICES * 256)
        ib[t] = 0xFFFFu;
}

// ---------------------------------------------------------------------------
// Kernel 1: grouped conv (k=3,pad 1) + ReLU + 1x1 conv via bf16 MFMA.
// grid = (17 t-tiles of 64, 32 batches), block = 256 (4 waves = 4 groups).
// Wave g: 4x6 MFMA register tile; per kstep: 4 ds_read_b128 A-frags +
// 6 coalesced 16B B-frags + 24 MFMAs. Direct pred write, no atomics.
// ---------------------------------------------------------------------------
__global__ __launch_bounds__(256) void conv_mfma_kernel(const float* __restrict__ phoneme,
                                                        const float* __restrict__ silence,
                                                        const float* __restrict__ b1,
                                                        const float* __restrict__ w2,
                                                        const float* __restrict__ b2,
                                                        const unsigned short* __restrict__ wpack,
                                                        float* __restrict__ pred) {
    const int b = blockIdx.y;
    const int t0 = blockIdx.x * 64;
    const int tid = threadIdx.x;

    __shared__ __align__(16) unsigned short xs[66][392];  // rows t0-1..t0+64, all 384 ch
    __shared__ float red[4][64];

    // Stage 66 full rows (fp32 -> bf16), coalesced full-row float4 reads
    for (int e = tid; e < 66 * 96; e += 256) {
        int row = e / 96;
        int v = e - row * 96;
        int r = t0 - 1 + row;
        float4 val;
        if (r < 0 || r > T_IN) {
            val = make_float4(0.f, 0.f, 0.f, 0.f);
        } else if (r == T_IN) {
            val = *(const float4*)(silence + v * 4);
        } else {
            val = *(const float4*)(phoneme + ((size_t)(b * T_IN + r)) * EMB + v * 4);
        }
        ushort4 pk;
        pk.x = f2bf(val.x); pk.y = f2bf(val.y); pk.z = f2bf(val.z); pk.w = f2bf(val.w);
        *(ushort4*)&xs[row][v * 4] = pk;
    }
    __syncthreads();

    const int g = tid >> 6;     // wave = group
    const int lane = tid & 63;
    const int quad = lane >> 4;
    const int lr = lane & 15;

    f32x4 acc[4][6];
#pragma unroll
    for (int mt = 0; mt < 4; ++mt)
#pragma unroll
        for (int nt = 0; nt < 6; ++nt) acc[mt][nt] = (f32x4){0.f, 0.f, 0.f, 0.f};

    const unsigned short* wg = wpack + (size_t)g * 9 * 6 * 512;

#pragma unroll
    for (int ks = 0; ks < 9; ++ks) {
        const int tap = ks / 3;                               // kstep-uniform
        const int col = g * GC + 32 * (ks % 3) + quad * 8;    // channel offset
        short8 a[4];
#pragma unroll
        for (int mt = 0; mt < 4; ++mt)
            a[mt] = *(const short8*)&xs[mt * 16 + lr + tap][col];
#pragma unroll
        for (int nt = 0; nt < 6; ++nt) {
            short8 bf = *(const short8*)(wg + ((size_t)(ks * 6 + nt) * 64 + lane) * 8);
#pragma unroll
            for (int mt = 0; mt < 4; ++mt)
                acc[mt][nt] = __builtin_amdgcn_mfma_f32_16x16x32_bf16(a[mt], bf, acc[mt][nt], 0, 0, 0);
        }
    }

    // Epilogue: bias + ReLU + w2-dot partials; m = mt*16 + quad*4 + reg, oc col = lr
    float s[4][4];
#pragma unroll
    for (int mt = 0; mt < 4; ++mt)
#pragma unroll
        for (int reg = 0; reg < 4; ++reg) s[mt][reg] = 0.f;
#pragma unroll
    for (int nt = 0; nt < 6; ++nt) {
        int oc = g * GC + nt * 16 + lr;
        float bias = b1[oc];
        float wc = w2[oc];
#pragma unroll
        for (int mt = 0; mt < 4; ++mt)
#pragma unroll
            for (int reg = 0; reg < 4; ++reg) {
                float h = acc[mt][nt][reg] + bias;
                h = h > 0.f ? h : 0.f;
                s[mt][reg] += wc * h;
            }
    }
    // butterfly-sum across the 16 lr lanes (stays within each 16-lane group)
#pragma unroll
    for (int off = 1; off < 16; off <<= 1)
#pragma unroll
        for (int mt = 0; mt < 4; ++mt)
#pragma unroll
            for (int reg = 0; reg < 4; ++reg)
                s[mt][reg] += __shfl_xor(s[mt][reg], off, 64);
#pragma unroll
    for (int mt = 0; mt < 4; ++mt)
#pragma unroll
        for (int reg = 0; reg < 4; ++reg)
            if (lr == mt * 4 + reg) red[g][mt * 16 + quad * 4 + reg] = s[mt][reg];
    __syncthreads();

    if (tid < 64) {
        int t = t0 + tid;
        if (t < TP)
            pred[b * TP + t] = red[0][tid] + red[1][tid] + red[2][tid] + red[3][tid] + b2[0];
    }
}

// ---------------------------------------------------------------------------
// Kernel 2: streaming gather via precomputed idx. No LDS, no sync, one
// float4 per thread, plain (cached) stores, full occupancy.
// grid = (ceil(t_out*96/256), 32).
// ---------------------------------------------------------------------------
__global__ __launch_bounds__(256) void gather_kernel(const float* __restrict__ phoneme,
                                                     const float* __restrict__ silence,
                                                     const unsigned short* __restrict__ idx,
                                                     float* __restrict__ out,
                                                     int t_out) {
    const int b = blockIdx.y;
    const int nfe = t_out * 96;
    int e = blockIdx.x * 256 + threadIdx.x;
    if (e >= nfe) return;
    int fl = e / 96;
    int v = e - fl * 96;
    unsigned short id = idx[(size_t)b * t_out + fl];
    f32x4 val;
    if (id == 0xFFFFu) {
        val = (f32x4){0.f, 0.f, 0.f, 0.f};
    } else if (id == T_IN) {
        val = ((const f32x4*)silence)[v];
    } else {
        val = ((const f32x4*)phoneme)[((size_t)b * T_IN + id) * 96 + v];
    }
    ((f32x4*)out)[(size_t)b * nfe + e] = val;
}

// ---------------------------------------------------------------------------
extern "C" void kernel_launch(void* const* d_in, const int* in_sizes, int n_in,
                              void* d_out, int out_size, void* d_ws, size_t ws_size,
                              hipStream_t stream) {
    const float* phoneme = (const float*)d_in[0];
    const float* silence = (const float*)d_in[1];
    const float* conv1_w = (const float*)d_in[2];
    const float* conv1_b = (const float*)d_in[3];
    const float* conv2_w = (const float*)d_in[4];
    const float* conv2_b = (const float*)d_in[5];
    const int* durations = (const int*)d_in[6];
    // d_in[7] = t_out on device; derive from out_size host-side instead.
    const int t_out = (out_size - BATCH * TP) / (BATCH * EMB);

    float* out_expanded = (float*)d_out;                            // [B, t_out, EMB]
    float* out_pred = (float*)d_out + (size_t)BATCH * t_out * EMB;  // [B, TP]

    // Workspace: idx [B][t_out] ushort, then wpack (16B-aligned)
    unsigned short* idx = (unsigned short*)d_ws;
    size_t idx_bytes = ((size_t)BATCH * t_out * sizeof(unsigned short) + 255) & ~(size_t)255;
    unsigned short* wpack = (unsigned short*)((char*)d_ws + idx_bytes);

    prep_scan_kernel<<<PREP_BLOCKS + BATCH * SCAT_SLICES, 256, 0, stream>>>(
        conv1_w, durations, wpack, idx, t_out);
    conv_mfma_kernel<<<dim3(17, BATCH), 256, 0, stream>>>(
        phoneme, silence, conv1_b, conv2_w, conv2_b, wpack, out_pred);
    gather_kernel<<<dim3((t_out * 96 + 255) / 256, BATCH), 256, 0, stream>>>(
        phoneme, silence, idx, out_expanded, t_out);
}

// Round 7
// 271.324 us; speedup vs baseline: 1.1114x; 1.0045x over previous
//
#include <hip/hip_runtime.h>

// Problem constants (match reference)
#define BATCH 32
#define T_IN 1024
#define TP 1025      // T+1 (phoneme + silence token)
#define EMB 384
#define GROUPS 4
#define GC 96        // channels per group

typedef __attribute__((ext_vector_type(8))) short short8;   // 8 bf16 (4 VGPRs)
typedef __attribute__((ext_vector_type(4))) float f32x4;    // 4 fp32 acc / 16B vec

#define N_WPACK (GROUPS * 9 * 6 * 64 * 8)   // 110592 bf16 elements
#define PREP_BLOCKS ((N_WPACK + 255) / 256) // 432
#define SCAT_SLICES 8                        // scatter blocks per batch
#define TOK_PER_SLICE 129                    // 8*129 = 1032 >= 1025
#define GITER 8                              // gather float4s per thread

__device__ __forceinline__ unsigned short f2bf(float f) {
    union { float f; unsigned u; } v; v.f = f;
    unsigned u = v.u + 0x7fffu + ((v.u >> 16) & 1u);  // RNE
    return (unsigned short)(u >> 16);
}

// ---------------------------------------------------------------------------
// Kernel 0 (fused): blocks [0,432) pack w1 -> bf16 MFMA B-frag layout;
// blocks [432, 432+256) : per-batch cumsum + scatter frame->token idx,
// 8 slice-blocks per batch (each redoes the cheap wave-scan, scatters its
// 129-token slice, and fills its share of the 0xFFFF tail).
// ---------------------------------------------------------------------------
__global__ __launch_bounds__(256) void prep_scan_kernel(const float* __restrict__ w1,
                                                        const int* __restrict__ dur,
                                                        unsigned short* __restrict__ wpack,
                                                        unsigned short* __restrict__ idx,
                                                        int t_out) {
    __shared__ int scum[TP];
    const int tid = threadIdx.x;

    if (blockIdx.x < PREP_BLOCKS) {
        int i = blockIdx.x * 256 + tid;
        if (i >= N_WPACK) return;
        int j = i & 7;
        int lane = (i >> 3) & 63;
        int rest = i >> 9;
        int nt = rest % 6; rest /= 6;
        int ks = rest % 9;
        int g = rest / 9;
        int oc = nt * 16 + (lane & 15);
        int kk = ks * 32 + (lane >> 4) * 8 + j;
        int k = kk / 96, ic = kk % 96;
        wpack[i] = f2bf(w1[((size_t)(g * GC + oc) * GC + ic) * 3 + k]);
        return;
    }

    const int sb = blockIdx.x - PREP_BLOCKS;     // 0..255
    const int b = sb >> 3;                       // batch
    const int slice = sb & 7;                    // slice within batch

    if (tid < 64) {
        const int* d = dur + b * TP;
        int offset = 0;
        for (int r = 0; r < 17; ++r) {
            int i2 = r * 64 + tid;
            int v = (i2 < TP) ? d[i2] : 0;
            int s = v;
#pragma unroll
            for (int off = 1; off < 64; off <<= 1) {
                int n = __shfl_up(s, off, 64);
                if (tid >= off) s += n;
            }
            if (i2 < TP) scum[i2] = s + offset;
            offset += __shfl(s, 63, 64);
        }
    }
    __syncthreads();

    unsigned short* ib = idx + (size_t)b * t_out;
    const int j0 = slice * TOK_PER_SLICE;
    const int j1 = min(TP, j0 + TOK_PER_SLICE);
    for (int j = j0 + tid; j < j1; j += 256) {
        int c = scum[j];
        int lo = j ? scum[j - 1] : 0;
        for (int f = lo; f < c; ++f) ib[f] = (unsigned short)j;
    }
    const int total = scum[TP - 1];
    for (int t = total + slice * 256 + tid; t < t_out; t += SCAT_SLICES * 256)
        ib[t] = 0xFFFFu;
}

// ---------------------------------------------------------------------------
// Kernel 1: grouped conv (k=3,pad 1) + ReLU + 1x1 conv via bf16 MFMA.
// grid = (17 t-tiles of 64, 32 batches), block = 256 (4 waves = 4 groups).
// Wave g: 4x6 MFMA register tile; per kstep: 4 ds_read_b128 A-frags +
// 6 coalesced 16B B-frags + 24 MFMAs. Direct pred write, no atomics.
// ---------------------------------------------------------------------------
__global__ __launch_bounds__(256) void conv_mfma_kernel(const float* __restrict__ phoneme,
                                                        const float* __restrict__ silence,
                                                        const float* __restrict__ b1,
                                                        const float* __restrict__ w2,
                                                        const float* __restrict__ b2,
                                                        const unsigned short* __restrict__ wpack,
                                                        float* __restrict__ pred) {
    const int b = blockIdx.y;
    const int t0 = blockIdx.x * 64;
    const int tid = threadIdx.x;

    __shared__ __align__(16) unsigned short xs[66][392];  // rows t0-1..t0+64, all 384 ch
    __shared__ float red[4][64];

    // Stage 66 full rows (fp32 -> bf16), coalesced full-row float4 reads
    for (int e = tid; e < 66 * 96; e += 256) {
        int row = e / 96;
        int v = e - row * 96;
        int r = t0 - 1 + row;
        float4 val;
        if (r < 0 || r > T_IN) {
            val = make_float4(0.f, 0.f, 0.f, 0.f);
        } else if (r == T_IN) {
            val = *(const float4*)(silence + v * 4);
        } else {
            val = *(const float4*)(phoneme + ((size_t)(b * T_IN + r)) * EMB + v * 4);
        }
        ushort4 pk;
        pk.x = f2bf(val.x); pk.y = f2bf(val.y); pk.z = f2bf(val.z); pk.w = f2bf(val.w);
        *(ushort4*)&xs[row][v * 4] = pk;
    }
    __syncthreads();

    const int g = tid >> 6;     // wave = group
    const int lane = tid & 63;
    const int quad = lane >> 4;
    const int lr = lane & 15;

    f32x4 acc[4][6];
#pragma unroll
    for (int mt = 0; mt < 4; ++mt)
#pragma unroll
        for (int nt = 0; nt < 6; ++nt) acc[mt][nt] = (f32x4){0.f, 0.f, 0.f, 0.f};

    const unsigned short* wg = wpack + (size_t)g * 9 * 6 * 512;

#pragma unroll
    for (int ks = 0; ks < 9; ++ks) {
        const int tap = ks / 3;                               // kstep-uniform
        const int col = g * GC + 32 * (ks % 3) + quad * 8;    // channel offset
        short8 a[4];
#pragma unroll
        for (int mt = 0; mt < 4; ++mt)
            a[mt] = *(const short8*)&xs[mt * 16 + lr + tap][col];
#pragma unroll
        for (int nt = 0; nt < 6; ++nt) {
            short8 bf = *(const short8*)(wg + ((size_t)(ks * 6 + nt) * 64 + lane) * 8);
#pragma unroll
            for (int mt = 0; mt < 4; ++mt)
                acc[mt][nt] = __builtin_amdgcn_mfma_f32_16x16x32_bf16(a[mt], bf, acc[mt][nt], 0, 0, 0);
        }
    }

    // Epilogue: bias + ReLU + w2-dot partials; m = mt*16 + quad*4 + reg, oc col = lr
    float s[4][4];
#pragma unroll
    for (int mt = 0; mt < 4; ++mt)
#pragma unroll
        for (int reg = 0; reg < 4; ++reg) s[mt][reg] = 0.f;
#pragma unroll
    for (int nt = 0; nt < 6; ++nt) {
        int oc = g * GC + nt * 16 + lr;
        float bias = b1[oc];
        float wc = w2[oc];
#pragma unroll
        for (int mt = 0; mt < 4; ++mt)
#pragma unroll
            for (int reg = 0; reg < 4; ++reg) {
                float h = acc[mt][nt][reg] + bias;
                h = h > 0.f ? h : 0.f;
                s[mt][reg] += wc * h;
            }
    }
    // butterfly-sum across the 16 lr lanes (stays within each 16-lane group)
#pragma unroll
    for (int off = 1; off < 16; off <<= 1)
#pragma unroll
        for (int mt = 0; mt < 4; ++mt)
#pragma unroll
            for (int reg = 0; reg < 4; ++reg)
                s[mt][reg] += __shfl_xor(s[mt][reg], off, 64);
#pragma unroll
    for (int mt = 0; mt < 4; ++mt)
#pragma unroll
        for (int reg = 0; reg < 4; ++reg)
            if (lr == mt * 4 + reg) red[g][mt * 16 + quad * 4 + reg] = s[mt][reg];
    __syncthreads();

    if (tid < 64) {
        int t = t0 + tid;
        if (t < TP)
            pred[b * TP + t] = red[0][tid] + red[1][tid] + red[2][tid] + red[3][tid] + b2[0];
    }
}

// ---------------------------------------------------------------------------
// Kernel 2: streaming gather via precomputed idx. No LDS, no sync.
// 8 float4s per thread (stride 256 apart -> coalesced), all loads issued
// before all stores -> 8 independent 16B loads in flight per thread.
// Grid ~5.5k blocks (vs 44k) to cut CP dispatch overhead.
// ---------------------------------------------------------------------------
__global__ __launch_bounds__(256) void gather_kernel(const float* __restrict__ phoneme,
                                                     const float* __restrict__ silence,
                                                     const unsigned short* __restrict__ idx,
                                                     float* __restrict__ out,
                                                     int t_out) {
    const int b = blockIdx.y;
    const int nfe = t_out * 96;
    const int base = blockIdx.x * (256 * GITER) + threadIdx.x;

    const unsigned short* ib = idx + (size_t)b * t_out;
    const f32x4* ph = (const f32x4*)phoneme + (size_t)b * T_IN * 96;
    const f32x4* s4 = (const f32x4*)silence;
    f32x4* ob = (f32x4*)out + (size_t)b * nfe;

    f32x4 v[GITER];
#pragma unroll
    for (int j = 0; j < GITER; ++j) {
        int e = base + j * 256;
        if (e < nfe) {
            int fl = e / 96;
            int c = e - fl * 96;
            unsigned short id = ib[fl];
            if (id == 0xFFFFu) {
                v[j] = (f32x4){0.f, 0.f, 0.f, 0.f};
            } else if (id == T_IN) {
                v[j] = s4[c];
            } else {
                v[j] = ph[(size_t)id * 96 + c];
            }
        }
    }
#pragma unroll
    for (int j = 0; j < GITER; ++j) {
        int e = base + j * 256;
        if (e < nfe) ob[e] = v[j];
    }
}

// ---------------------------------------------------------------------------
extern "C" void kernel_launch(void* const* d_in, const int* in_sizes, int n_in,
                              void* d_out, int out_size, void* d_ws, size_t ws_size,
                              hipStream_t stream) {
    const float* phoneme = (const float*)d_in[0];
    const float* silence = (const float*)d_in[1];
    const float* conv1_w = (const float*)d_in[2];
    const float* conv1_b = (const float*)d_in[3];
    const float* conv2_w = (const float*)d_in[4];
    const float* conv2_b = (const float*)d_in[5];
    const int* durations = (const int*)d_in[6];
    // d_in[7] = t_out on device; derive from out_size host-side instead.
    const int t_out = (out_size - BATCH * TP) / (BATCH * EMB);

    float* out_expanded = (float*)d_out;                            // [B, t_out, EMB]
    float* out_pred = (float*)d_out + (size_t)BATCH * t_out * EMB;  // [B, TP]

    // Workspace: idx [B][t_out] ushort, then wpack (16B-aligned)
    unsigned short* idx = (unsigned short*)d_ws;
    size_t idx_bytes = ((size_t)BATCH * t_out * sizeof(unsigned short) + 255) & ~(size_t)255;
    unsigned short* wpack = (unsigned short*)((char*)d_ws + idx_bytes);

    prep_scan_kernel<<<PREP_BLOCKS + BATCH * SCAT_SLICES, 256, 0, stream>>>(
        conv1_w, durations, wpack, idx, t_out);
    conv_mfma_kernel<<<dim3(17, BATCH), 256, 0, stream>>>(
        phoneme, silence, conv1_b, conv2_w, conv2_b, wpack, out_pred);
    gather_kernel<<<dim3((t_out * 96 + 256 * GITER - 1) / (256 * GITER), BATCH), 256, 0, stream>>>(
        phoneme, silence, idx, out_expanded, t_out);
}